// Round 9
// baseline (131.012 us; speedup 1.0000x reference)
//
#include <hip/hip_runtime.h>

#define CH 30
#define CELLS 49
#define ROWF 1470          // floats per batch row
#define RPB 4              // rows per block
#define WPB 4              // waves per block (256 threads)

__device__ __forceinline__ float waveReduce(float v) {
    #pragma unroll
    for (int o = 32; o > 0; o >>= 1) v += __shfl_xor(v, o, 64);
    return v;
}

// R9: separate the regimes. Bulk read = pure dense TLP stream (the G13/m219
// recipe: float4 loads, independent addresses, 32 waves/CU, zero dependency
// structure -- the pattern that hits 80%+ HBM). Dependent logic (mask build,
// box/IoU) = tiny per-wave phases amortized across 8 resident blocks/CU.
//   prologue: per wave, 4 conf gathers for its row -> ballot -> mask + noobj
//   stream:   block's 4 rows as ~1470 float4 x2 tensors, cls only, mask via
//             broadcast ds_read of lmask[row_local]
//   epilogue: R7-style box gathers (L2/L3-warm) -> IoU -> coord + obj-conf
// LDS ~7 KB, no launch_bounds cap needed; one barrier after mask publish.
__global__ __launch_bounds__(256) void yolo_main(const float* __restrict__ pred,
                                                 const float* __restrict__ targ,
                                                 float* __restrict__ ws, int B,
                                                 int NB) {
    const int w = threadIdx.x >> 6;
    const int lane = threadIdx.x & 63;
    const int r0 = blockIdx.x * RPB;         // block's first row
    const int myrow = r0 + w;                // this wave's row
    const int nrows = (B - r0) < RPB ? (B - r0) : RPB;   // block-uniform

    __shared__ unsigned long long lmask[RPB];
    __shared__ float4 boxS[WPB][2 * CELLS];  // pred boxes xyxy (broadcast reads)
    __shared__ int clist[WPB][CELLS];
    __shared__ float sred[WPB][3];

    float cls = 0.f, objc = 0.f, coord = 0.f;
    unsigned long long mymask = 0ull;

    // ---- prologue: per-wave conf gathers -> mask + noobj loss ----
    if (w < nrows) {                         // wave-uniform
        const float* P = pred + (size_t)myrow * ROWF;
        const float* T = targ + (size_t)myrow * ROWF;
        const int cl = lane < CELLS ? lane : CELLS - 1;
        const float t4 = T[cl * CH + 4];
        const float p4 = P[cl * CH + 4];
        const float t9 = T[cl * CH + 9];
        const float p9 = P[cl * CH + 9];
        const bool act = lane < CELLS;
        const bool isObj = act && (t4 > 0.f);
        mymask = __ballot(isObj);
        if (act && !isObj) {                 // noobj conf loss (0.5 folded)
            const float d4 = p4 - t4, d9 = p9 - t9;
            objc += 0.5f * (d4 * d4 + d9 * d9);
        }
        if (lane == 0) lmask[w] = mymask;
    } else if (w < RPB && lane == 0) {
        lmask[w] = 0ull;
    }
    __syncthreads();                         // publish masks for the stream

    // ---- dense stream: block's rows, float4-vectorized, cls only ----
    // Block base = r0*5880 B, 16B-aligned for any r0 (5880%8==0, RPB*5880%16==0).
    {
        const float4* Pb = (const float4*)(pred + (size_t)r0 * ROWF);
        const float4* Tb = (const float4*)(targ + (size_t)r0 * ROWF);
        const int npair = nrows * 735;       // float2 pairs in block region
        const int nq4 = npair >> 1;          // full float4s (npair even for nrows%2==0)
        for (int i = threadIdx.x; i < nq4; i += 256) {
            const float4 pv = Pb[i];
            const float4 tv = Tb[i];
            #pragma unroll
            for (int k = 0; k < 2; ++k) {
                const int p = 2 * i + k;
                const int rl = (p * 5707) >> 22;      // p/735, valid p<2940
                const int pr = p - rl * 735;
                const int cell = (pr * 17477) >> 18;  // pr/15, valid pr<768
                const int ch0 = 2 * (pr - cell * 15);
                const unsigned long long mk = lmask[rl];  // 2-way bcast, free
                const float wobj = (float)((mk >> cell) & 1ull);
                const float dx = (k ? pv.z : pv.x) - (k ? tv.z : tv.x);
                const float dy = (k ? pv.w : pv.y) - (k ? tv.w : tv.y);
                cls += (ch0 >= 10) ? wobj * (dx * dx + dy * dy) : 0.f;
            }
        }
        if (npair & 1) {                     // odd-nrows tail: last lone pair
            const int p = npair - 1;
            if (threadIdx.x == 0) {
                const int rl = (p * 5707) >> 22;
                const int pr = p - rl * 735;
                const int cell = (pr * 17477) >> 18;
                const int ch0 = 2 * (pr - cell * 15);
                const float* Pf = pred + (size_t)r0 * ROWF + 2 * p;
                const float* Tf = targ + (size_t)r0 * ROWF + 2 * p;
                const float wobj = (float)((lmask[rl] >> cell) & 1ull);
                const float dx = Pf[0] - Tf[0], dy = Pf[1] - Tf[1];
                cls += (ch0 >= 10) ? wobj * (dx * dx + dy * dy) : 0.f;
            }
        }
    }

    // ---- epilogue: box/IoU for this wave's row (gathers are cache-warm) ----
    if (w < nrows && mymask) {               // wave-uniform
        const float* P = pred + (size_t)myrow * ROWF;
        const float* T = targ + (size_t)myrow * ROWF;
        const int nBox = 2 * __popcll(mymask);
        const bool isObj = (lane < CELLS) && ((mymask >> lane) & 1ull);
        if (isObj) clist[w][__popcll(mymask & ((1ull << lane) - 1ull))] = lane;

        // issue ALL box gathers back-to-back (e-rounds lane, lane+64)
        const int e0 = lane, e1 = lane + 64;
        const int c0 = clist[w][(e0 < nBox ? e0 : 0) >> 1];
        const int c1 = clist[w][(e1 < nBox ? e1 : 0) >> 1];
        const int b0 = c0 * CH + (e0 & 1) * 5;
        const int b1 = c1 * CH + (e1 & 1) * 5;
        const float4 pB0 = *(const float4*)(P + b0);
        const float4 tB0 = *(const float4*)(T + b0);
        const float pE0 = P[b0 + 4], tE0 = T[b0 + 4];
        const float4 pB1 = *(const float4*)(P + b1);
        const float4 tB1 = *(const float4*)(T + b1);
        const float pE1 = P[b1 + 4], tE1 = T[b1 + 4];

        if (e0 < nBox)
            boxS[w][e0] = make_float4(pB0.x - 0.5f * pB0.z, pB0.y - 0.5f * pB0.w,
                                      pB0.x + 0.5f * pB0.z, pB0.y + 0.5f * pB0.w);
        if (e1 < nBox)
            boxS[w][e1] = make_float4(pB1.x - 0.5f * pB1.z, pB1.y - 0.5f * pB1.w,
                                      pB1.x + 0.5f * pB1.z, pB1.y + 0.5f * pB1.w);

        #pragma unroll
        for (int eh = 0; eh < 2; ++eh) {
            const int e = eh ? e1 : e0;
            if (e < nBox) {
                const float4 tb = eh ? tB1 : tB0;
                const float4 pb = eh ? pB1 : pB0;
                const float pe = eh ? pE1 : pE0;
                const float te = eh ? tE1 : tE0;
                const float tx1 = tb.x - 0.5f * tb.z, ty1 = tb.y - 0.5f * tb.w;
                const float tx2 = tb.x + 0.5f * tb.z, ty2 = tb.y + 0.5f * tb.w;
                const float ta = (tx2 - tx1) * (ty2 - ty1);
                float maxiou = 0.f;
                for (int i = 0; i < nBox; ++i) {
                    const float4 pb4 = boxS[w][i];   // uniform addr = broadcast
                    const float lx = fmaxf(pb4.x, tx1), ly = fmaxf(pb4.y, ty1);
                    const float rx = fminf(pb4.z, tx2), ry = fminf(pb4.w, ty2);
                    const float iw = fmaxf(rx - lx, 0.f), ih = fmaxf(ry - ly, 0.f);
                    const float inter = iw * ih;
                    const float pa = (pb4.z - pb4.x) * (pb4.w - pb4.y);
                    const float un = pa + ta - inter;
                    const float iou = inter / (un > 0.f ? un : 1.f);
                    maxiou = fmaxf(maxiou, iou);
                }
                if (maxiou != 0.f) {                 // cmask
                    const float dcx = pb.x - tb.x, dcy = pb.y - tb.y;
                    coord += dcx * dcx + dcy * dcy;
                    const float dw = sqrtf(pb.z) - sqrtf(tb.z);
                    const float dh = sqrtf(pb.w) - sqrtf(tb.w);
                    coord += dw * dw + dh * dh;
                    const float dc = pe - te;
                    objc += dc * dc;
                }
            }
        }
    }

    // ---- wave reduce, then block reduce (one barrier), one triple per block ----
    cls = waveReduce(cls); objc = waveReduce(objc); coord = waveReduce(coord);
    if (lane == 0) { sred[w][0] = cls; sred[w][1] = objc; sred[w][2] = coord; }
    __syncthreads();
    if (threadIdx.x == 0) {
        float C = 0.f, O = 0.f, X = 0.f;
        #pragma unroll
        for (int k = 0; k < WPB; ++k) { C += sred[k][0]; O += sred[k][1]; X += sred[k][2]; }
        ws[blockIdx.x] = C;
        ws[NB + blockIdx.x] = O;
        ws[2 * NB + blockIdx.x] = X;
    }
}

__global__ __launch_bounds__(1024) void yolo_reduce(const float* __restrict__ ws,
                                                    float* __restrict__ out,
                                                    int NB, float invB) {
    const int tid = threadIdx.x;
    const int w = tid >> 6, lane = tid & 63;
    float c = 0.f, o = 0.f, x = 0.f;
    for (int i = tid; i < NB; i += 1024) {
        c += ws[i];
        o += ws[NB + i];
        x += ws[2 * NB + i];
    }
    c = waveReduce(c); o = waveReduce(o); x = waveReduce(x);
    __shared__ float sred[16][3];
    if (lane == 0) { sred[w][0] = c; sred[w][1] = o; sred[w][2] = x; }
    __syncthreads();
    if (tid == 0) {
        float C = 0.f, O = 0.f, X = 0.f;
        #pragma unroll
        for (int k = 0; k < 16; ++k) { C += sred[k][0]; O += sred[k][1]; X += sred[k][2]; }
        const float bcls = C * invB;
        const float bobj = O * invB;          // noobj*0.5 folded upstream
        const float bcoord = X * 5.0f * invB; // COORD_LAMBDA
        out[0] = bcls + bobj + bcoord;
        out[1] = bcls;
        out[2] = bobj;
        out[3] = bcoord;
    }
}

extern "C" void kernel_launch(void* const* d_in, const int* in_sizes, int n_in,
                              void* d_out, int out_size, void* d_ws, size_t ws_size,
                              hipStream_t stream) {
    const float* pred = (const float*)d_in[0];
    const float* targ = (const float*)d_in[1];
    float* ws = (float*)d_ws;
    float* out = (float*)d_out;
    const int B = in_sizes[0] / ROWF;
    const int NB = (B + RPB - 1) / RPB;

    yolo_main<<<NB, 256, 0, stream>>>(pred, targ, ws, B, NB);
    yolo_reduce<<<1, 1024, 0, stream>>>(ws, out, NB, 1.0f / (float)B);
}